// Round 5
// baseline (6754.386 us; speedup 1.0000x reference)
//
#include <hip/hip_runtime.h>
#include <hip/hip_bf16.h>

// E71 Delta cell: T=2048, B=16, D=1024, N=128
// proj layout in ws: [t][b][512] f32, cols 0..127=k_hat (after norm pass),
// 128..255=v, 256..383=q, 384..511=bx

#define T_STEPS 2048
#define NB 16
#define ND 128
#define KD 1024
#define PSTRIDE 512

typedef __attribute__((ext_vector_type(4))) float f32x4;
typedef __attribute__((ext_vector_type(8))) short short8v;

__device__ __forceinline__ unsigned short f2bf(float f) {
  union { float f; unsigned int u; } c; c.f = f;
  unsigned int u = c.u;
  unsigned int r = u + 0x7fffu + ((u >> 16) & 1u);   // round-to-nearest-even
  return (unsigned short)(r >> 16);
}

// ---------------------------------------------------------------------------
// Projection GEMM (unchanged, ~56us): bf16 MFMA, 128x128 tile, BK=64,
// XOR-swizzled LDS.
// ---------------------------------------------------------------------------
__global__ __launch_bounds__(256) void proj_gemm(
    const float* __restrict__ X,
    const float* __restrict__ Wk, const float* __restrict__ Wv,
    const float* __restrict__ Wq, const float* __restrict__ Wb,
    float* __restrict__ C)
{
  __shared__ unsigned short As[128 * 64];
  __shared__ unsigned short Bs[128 * 64];
  const int tid = threadIdx.x;
  const int bm = blockIdx.x;
  const int bn = blockIdx.y;
  const float* W = (bn == 0) ? Wk : ((bn == 1) ? Wv : ((bn == 2) ? Wq : Wb));
  const int lane = tid & 63;
  const int wave = tid >> 6;
  const int wr = wave >> 1, wc = wave & 1;

  f32x4 acc[4][4];
#pragma unroll
  for (int i = 0; i < 4; i++)
#pragma unroll
    for (int j = 0; j < 4; j++) acc[i][j] = (f32x4){0.f, 0.f, 0.f, 0.f};

  for (int k0 = 0; k0 < KD; k0 += 64) {
    __syncthreads();
#pragma unroll
    for (int c = 0; c < 4; c++) {
      const int g = tid + c * 256;
      const int row = g >> 3;
      const int ch = g & 7;
      const int pos = ((ch ^ (row & 7)) * 8);
      {
        const float* ga = X + (size_t)(bm * 128 + row) * KD + k0 + ch * 8;
        float4 f0 = *(const float4*)(ga);
        float4 f1 = *(const float4*)(ga + 4);
        union { unsigned short u[8]; short8v v; } pk2;
        pk2.u[0] = f2bf(f0.x); pk2.u[1] = f2bf(f0.y);
        pk2.u[2] = f2bf(f0.z); pk2.u[3] = f2bf(f0.w);
        pk2.u[4] = f2bf(f1.x); pk2.u[5] = f2bf(f1.y);
        pk2.u[6] = f2bf(f1.z); pk2.u[7] = f2bf(f1.w);
        *reinterpret_cast<short8v*>(&As[row * 64 + pos]) = pk2.v;
      }
      {
        const float* gb = W + (size_t)row * KD + k0 + ch * 8;
        float4 f0 = *(const float4*)(gb);
        float4 f1 = *(const float4*)(gb + 4);
        union { unsigned short u[8]; short8v v; } pk2;
        pk2.u[0] = f2bf(f0.x); pk2.u[1] = f2bf(f0.y);
        pk2.u[2] = f2bf(f0.z); pk2.u[3] = f2bf(f0.w);
        pk2.u[4] = f2bf(f1.x); pk2.u[5] = f2bf(f1.y);
        pk2.u[6] = f2bf(f1.z); pk2.u[7] = f2bf(f1.w);
        *reinterpret_cast<short8v*>(&Bs[row * 64 + pos]) = pk2.v;
      }
    }
    __syncthreads();
#pragma unroll
    for (int kk = 0; kk < 2; kk++) {
      const int ch = kk * 4 + (lane >> 4);
      short8v a[4], b[4];
#pragma unroll
      for (int i = 0; i < 4; i++) {
        const int ar = wr * 64 + i * 16 + (lane & 15);
        a[i] = *reinterpret_cast<const short8v*>(&As[ar * 64 + ((ch ^ (ar & 7)) * 8)]);
        const int br = wc * 64 + i * 16 + (lane & 15);
        b[i] = *reinterpret_cast<const short8v*>(&Bs[br * 64 + ((ch ^ (br & 7)) * 8)]);
      }
#pragma unroll
      for (int i = 0; i < 4; i++)
#pragma unroll
        for (int j = 0; j < 4; j++)
          acc[i][j] = __builtin_amdgcn_mfma_f32_16x16x32_bf16(a[i], b[j], acc[i][j], 0, 0, 0);
    }
  }
#pragma unroll
  for (int i = 0; i < 4; i++)
#pragma unroll
    for (int j = 0; j < 4; j++)
#pragma unroll
      for (int r = 0; r < 4; r++) {
        const int row = bm * 128 + wr * 64 + i * 16 + (lane >> 4) * 4 + r;
        const int col = bn * 128 + wc * 64 + j * 16 + (lane & 15);
        C[(size_t)row * PSTRIDE + col] = acc[i][j][r];
      }
}

// ---------------------------------------------------------------------------
// k-normalization pre-pass: proj[row][0:128] <- k / (||k|| + eps).
// ---------------------------------------------------------------------------
__global__ __launch_bounds__(256) void norm_k(float* __restrict__ proj) {
  const int lane = threadIdx.x & 63;
  const int wid = (blockIdx.x * 256 + threadIdx.x) >> 6;
  float* rowp = proj + (size_t)wid * PSTRIDE;
  float2 kv = *reinterpret_cast<float2*>(rowp + lane * 2);
  float ss = kv.x * kv.x + kv.y * kv.y;
  ss += __shfl_xor(ss, 1);
  ss += __shfl_xor(ss, 2);
  ss += __shfl_xor(ss, 4);
  ss += __shfl_xor(ss, 8);
  ss += __shfl_xor(ss, 16);
  ss += __shfl_xor(ss, 32);
  const float rn = 1.0f / (sqrtf(ss) + 1e-6f);
  kv.x *= rn; kv.y *= rn;
  *reinterpret_cast<float2*>(rowp + lane * 2) = kv;
}

// ---------------------------------------------------------------------------
// Sequential scan, pure-register, zero LDS, zero barriers.
// R5 geometry: 16 blocks x 1024 threads. Block = batch; wave = row-group.
//   -> 4 independent chains per SIMD (TLP hides chain stalls), and all 16
//      waves of a block read the SAME 2KB proj row each step -> L1-served
//      after the first toucher (16x less L2/L3 latency exposure).
// Lane mapping: col-block c = lane bits{0,1,3}, local row = bits{2,4,5}
//   -> 8-lane reductions all-DPP: xor1 (quad_perm 0xB1), xor2 (0x4E),
//      xor8 (row_ror:8).
// Depth-4 register prefetch ring (A..D) fenced with sched_barrier(0);
// silu+store of step t deferred to slot t+1 (off the recurrence chain).
// ---------------------------------------------------------------------------
__device__ __forceinline__ float sum8d(float v) {
  v += __int_as_float(__builtin_amdgcn_update_dpp(0, __float_as_int(v), 0xB1, 0xF, 0xF, true));   // xor 1
  v += __int_as_float(__builtin_amdgcn_update_dpp(0, __float_as_int(v), 0x4E, 0xF, 0xF, true));   // xor 2
  v += __int_as_float(__builtin_amdgcn_update_dpp(0, __float_as_int(v), 0x128, 0xF, 0xF, true));  // row_ror:8 == xor 8
  return v;
}

struct Buf { f32x4 kn[4]; f32x4 q[4]; float v, bx; };

__device__ __forceinline__ void load_buf(const float* __restrict__ p, int c, int row, Buf& b) {
  const f32x4* p4 = reinterpret_cast<const f32x4*>(p);
#pragma unroll
  for (int j = 0; j < 4; j++) b.kn[j] = p4[c * 4 + j];
#pragma unroll
  for (int j = 0; j < 4; j++) b.q[j] = p4[64 + c * 4 + j];
  b.v = p[128 + row];
  b.bx = p[384 + row];
}

__device__ __forceinline__ float core(const Buf& b, float db, float bb, f32x4 S4[4]) {
  f32x4 a0 = S4[0] * b.kn[0];
  f32x4 a1 = S4[1] * b.kn[1];
  a0 = __builtin_elementwise_fma(S4[2], b.kn[2], a0);
  a1 = __builtin_elementwise_fma(S4[3], b.kn[3], a1);
  const f32x4 acc = a0 + a1;
  const float r = sum8d((acc.x + acc.y) + (acc.z + acc.w));
  const float lg = fmaf(db, r, b.bx + bb);
  const float beta = __builtin_amdgcn_rcpf(1.0f + __expf(-lg));
  const float cr = beta * (b.v - r);
  const f32x4 cr4 = {cr, cr, cr, cr};
#pragma unroll
  for (int j = 0; j < 4; j++) S4[j] = __builtin_elementwise_fma(cr4, b.kn[j], S4[j]);
  f32x4 o0 = S4[0] * b.q[0];
  f32x4 o1 = S4[1] * b.q[1];
  o0 = __builtin_elementwise_fma(S4[2], b.q[2], o0);
  o1 = __builtin_elementwise_fma(S4[3], b.q[3], o1);
  const f32x4 ao = o0 + o1;
  return sum8d((ao.x + ao.y) + (ao.z + ao.w));     // raw od; silu deferred
}

__device__ __forceinline__ float fin(float od) {
  return od * od * __builtin_amdgcn_rcpf(1.0f + __expf(-od));
}

__global__ __launch_bounds__(1024) void scan_kernel(
    const float* __restrict__ proj, const float* __restrict__ S_in,
    const float* __restrict__ d_beta, const float* __restrict__ b_beta,
    float* __restrict__ out, float* __restrict__ S_out)
{
  const int lane = threadIdx.x & 63;
  const int batch = blockIdx.x;            // block = batch
  const int wv = threadIdx.x >> 6;         // wave = row-group 0..15
  const int c = (lane & 3) | ((lane & 8) >> 1);                    // bits {0,1,3}
  const int rloc = ((lane >> 2) & 1) | (((lane >> 4) & 3) << 1);   // bits {2,4,5}
  const int row = wv * 8 + rloc;
  const bool w0 = ((lane & 11) == 0);      // c == 0: one lane per row stores

  f32x4 S4[4];
  {
    const f32x4* Sp4 = reinterpret_cast<const f32x4*>(
        S_in + ((size_t)batch * ND + row) * ND + c * 16);
#pragma unroll
    for (int j = 0; j < 4; j++) S4[j] = Sp4[j];
  }
  const float db = d_beta[row];
  const float bb = b_beta[row];

  const float* pb = proj + (size_t)batch * PSTRIDE;
  const size_t sstep = (size_t)NB * PSTRIDE;
  float* outp = out + (size_t)batch * ND + row;
  const size_t ostep = (size_t)NB * ND;

  Buf A, B, C, D;
  __builtin_amdgcn_sched_barrier(0);
  load_buf(pb + 0 * sstep, c, row, A);
  load_buf(pb + 1 * sstep, c, row, B);
  load_buf(pb + 2 * sstep, c, row, C);
  load_buf(pb + 3 * sstep, c, row, D);
  __builtin_amdgcn_sched_barrier(0);

  float od_prev;

#define SLOT(BUF, tnext)                                                  \
  do {                                                                    \
    const float gprev = fin(od_prev);                                     \
    if (w0) *outp = gprev;                                                \
    outp += ostep;                                                        \
    od_prev = core(BUF, db, bb, S4);                                      \
    __builtin_amdgcn_sched_barrier(0);                                    \
    load_buf(pb + (size_t)(tnext) * sstep, c, row, BUF);                  \
    __builtin_amdgcn_sched_barrier(0);                                    \
  } while (0)

  // peel: step 0 has no pending store
  od_prev = core(A, db, bb, S4);
  __builtin_amdgcn_sched_barrier(0);
  load_buf(pb + 4 * sstep, c, row, A);
  __builtin_amdgcn_sched_barrier(0);
  SLOT(B, 5);
  SLOT(C, 6);
  SLOT(D, 7);

  for (int t = 4; t < T_STEPS; t += 4) {
    const int t4 = (t + 4 < T_STEPS) ? t + 4 : T_STEPS - 1;
    const int t5 = (t + 5 < T_STEPS) ? t + 5 : T_STEPS - 1;
    const int t6 = (t + 6 < T_STEPS) ? t + 6 : T_STEPS - 1;
    const int t7 = (t + 7 < T_STEPS) ? t + 7 : T_STEPS - 1;
    SLOT(A, t4);
    SLOT(B, t5);
    SLOT(C, t6);
    SLOT(D, t7);
  }
  // final pending store (step 2047)
  {
    const float g = fin(od_prev);
    if (w0) *outp = g;
  }
#undef SLOT

  {
    f32x4* So4 = reinterpret_cast<f32x4*>(
        S_out + ((size_t)batch * ND + row) * ND + c * 16);
#pragma unroll
    for (int j = 0; j < 4; j++) So4[j] = S4[j];
  }
}

extern "C" void kernel_launch(void* const* d_in, const int* in_sizes, int n_in,
                              void* d_out, int out_size, void* d_ws, size_t ws_size,
                              hipStream_t stream) {
  const float* x  = (const float*)d_in[0];   // [2048][16][1024]
  const float* S0 = (const float*)d_in[1];   // [16][128][128]
  const float* Wk = (const float*)d_in[2];
  const float* Wv = (const float*)d_in[3];
  const float* Wq = (const float*)d_in[4];
  const float* Wb = (const float*)d_in[5];
  const float* db = (const float*)d_in[6];
  const float* bb = (const float*)d_in[7];
  float* out  = (float*)d_out;                           // [2048][16][128]
  float* Sout = out + (size_t)T_STEPS * NB * ND;         // [16][128][128]
  float* proj = (float*)d_ws;                            // [32768][512] = 64 MB

  dim3 ggrid(256, 4);
  proj_gemm<<<ggrid, 256, 0, stream>>>(x, Wk, Wv, Wq, Wb, proj);
  norm_k<<<8192, 256, 0, stream>>>(proj);
  scan_kernel<<<16, 1024, 0, stream>>>(proj, S0, db, bb, out, Sout);
}

// Round 6
// 511.858 us; speedup vs baseline: 13.1958x; 13.1958x over previous
//
#include <hip/hip_runtime.h>
#include <hip/hip_bf16.h>

// E71 Delta cell: T=2048, B=16, D=1024, N=128
// proj layout in ws: [t][b][512] f32, cols 0..127=k_hat (after norm pass),
// 128..255=v, 256..383=q, 384..511=bx

#define T_STEPS 2048
#define NB 16
#define ND 128
#define KD 1024
#define PSTRIDE 512

typedef __attribute__((ext_vector_type(4))) float f32x4;
typedef __attribute__((ext_vector_type(2))) float f32x2;
typedef __attribute__((ext_vector_type(8))) short short8v;

__device__ __forceinline__ unsigned short f2bf(float f) {
  union { float f; unsigned int u; } c; c.f = f;
  unsigned int u = c.u;
  unsigned int r = u + 0x7fffu + ((u >> 16) & 1u);   // round-to-nearest-even
  return (unsigned short)(r >> 16);
}

// ---------------------------------------------------------------------------
// Projection GEMM (unchanged, ~56us): bf16 MFMA, 128x128 tile, BK=64,
// XOR-swizzled LDS.
// ---------------------------------------------------------------------------
__global__ __launch_bounds__(256) void proj_gemm(
    const float* __restrict__ X,
    const float* __restrict__ Wk, const float* __restrict__ Wv,
    const float* __restrict__ Wq, const float* __restrict__ Wb,
    float* __restrict__ C)
{
  __shared__ unsigned short As[128 * 64];
  __shared__ unsigned short Bs[128 * 64];
  const int tid = threadIdx.x;
  const int bm = blockIdx.x;
  const int bn = blockIdx.y;
  const float* W = (bn == 0) ? Wk : ((bn == 1) ? Wv : ((bn == 2) ? Wq : Wb));
  const int lane = tid & 63;
  const int wave = tid >> 6;
  const int wr = wave >> 1, wc = wave & 1;

  f32x4 acc[4][4];
#pragma unroll
  for (int i = 0; i < 4; i++)
#pragma unroll
    for (int j = 0; j < 4; j++) acc[i][j] = (f32x4){0.f, 0.f, 0.f, 0.f};

  for (int k0 = 0; k0 < KD; k0 += 64) {
    __syncthreads();
#pragma unroll
    for (int c = 0; c < 4; c++) {
      const int g = tid + c * 256;
      const int row = g >> 3;
      const int ch = g & 7;
      const int pos = ((ch ^ (row & 7)) * 8);
      {
        const float* ga = X + (size_t)(bm * 128 + row) * KD + k0 + ch * 8;
        float4 f0 = *(const float4*)(ga);
        float4 f1 = *(const float4*)(ga + 4);
        union { unsigned short u[8]; short8v v; } pk2;
        pk2.u[0] = f2bf(f0.x); pk2.u[1] = f2bf(f0.y);
        pk2.u[2] = f2bf(f0.z); pk2.u[3] = f2bf(f0.w);
        pk2.u[4] = f2bf(f1.x); pk2.u[5] = f2bf(f1.y);
        pk2.u[6] = f2bf(f1.z); pk2.u[7] = f2bf(f1.w);
        *reinterpret_cast<short8v*>(&As[row * 64 + pos]) = pk2.v;
      }
      {
        const float* gb = W + (size_t)row * KD + k0 + ch * 8;
        float4 f0 = *(const float4*)(gb);
        float4 f1 = *(const float4*)(gb + 4);
        union { unsigned short u[8]; short8v v; } pk2;
        pk2.u[0] = f2bf(f0.x); pk2.u[1] = f2bf(f0.y);
        pk2.u[2] = f2bf(f0.z); pk2.u[3] = f2bf(f0.w);
        pk2.u[4] = f2bf(f1.x); pk2.u[5] = f2bf(f1.y);
        pk2.u[6] = f2bf(f1.z); pk2.u[7] = f2bf(f1.w);
        *reinterpret_cast<short8v*>(&Bs[row * 64 + pos]) = pk2.v;
      }
    }
    __syncthreads();
#pragma unroll
    for (int kk = 0; kk < 2; kk++) {
      const int ch = kk * 4 + (lane >> 4);
      short8v a[4], b[4];
#pragma unroll
      for (int i = 0; i < 4; i++) {
        const int ar = wr * 64 + i * 16 + (lane & 15);
        a[i] = *reinterpret_cast<const short8v*>(&As[ar * 64 + ((ch ^ (ar & 7)) * 8)]);
        const int br = wc * 64 + i * 16 + (lane & 15);
        b[i] = *reinterpret_cast<const short8v*>(&Bs[br * 64 + ((ch ^ (br & 7)) * 8)]);
      }
#pragma unroll
      for (int i = 0; i < 4; i++)
#pragma unroll
        for (int j = 0; j < 4; j++)
          acc[i][j] = __builtin_amdgcn_mfma_f32_16x16x32_bf16(a[i], b[j], acc[i][j], 0, 0, 0);
    }
  }
#pragma unroll
  for (int i = 0; i < 4; i++)
#pragma unroll
    for (int j = 0; j < 4; j++)
#pragma unroll
      for (int r = 0; r < 4; r++) {
        const int row = bm * 128 + wr * 64 + i * 16 + (lane >> 4) * 4 + r;
        const int col = bn * 128 + wc * 64 + j * 16 + (lane & 15);
        C[(size_t)row * PSTRIDE + col] = acc[i][j][r];
      }
}

// ---------------------------------------------------------------------------
// k-normalization pre-pass: proj[row][0:128] <- k / (||k|| + eps).
// ---------------------------------------------------------------------------
__global__ __launch_bounds__(256) void norm_k(float* __restrict__ proj) {
  const int lane = threadIdx.x & 63;
  const int wid = (blockIdx.x * 256 + threadIdx.x) >> 6;
  float* rowp = proj + (size_t)wid * PSTRIDE;
  float2 kv = *reinterpret_cast<float2*>(rowp + lane * 2);
  float ss = kv.x * kv.x + kv.y * kv.y;
  ss += __shfl_xor(ss, 1);
  ss += __shfl_xor(ss, 2);
  ss += __shfl_xor(ss, 4);
  ss += __shfl_xor(ss, 8);
  ss += __shfl_xor(ss, 16);
  ss += __shfl_xor(ss, 32);
  const float rn = 1.0f / (sqrtf(ss) + 1e-6f);
  kv.x *= rn; kv.y *= rn;
  *reinterpret_cast<float2*>(rowp + lane * 2) = kv;
}

// ---------------------------------------------------------------------------
// Sequential scan, pure-register, zero barriers.
// R6 geometry: 512 blocks x 64 threads; block = (batch, 4-row group).
//   16 lanes per row (cc = lane bits{0,1,2,3} -> 8 cols each), 4 rows/wave
//   (rloc = bits{4,5}). Halves per-step VALU issue vs 8-lane/row (pk math on
//   8-float slices) and cuts loads 10 -> 6. 2 blocks/CU (bid, bid+256 = same
//   batch -> shared L1 window); all 256 CUs busy.
// Reduction over 16 lanes: xor1 (quad_perm 0xB1), xor2 (0x4E),
//   xor8 (row_ror:8), xor4 (ds_swizzle 0x101F) - 3 DPP + 1 swizzle.
// Depth-4 register prefetch ring (A..D) fenced with sched_barrier(0) (R4's
// proven mechanism); silu+store of step t deferred to slot t+1.
// ---------------------------------------------------------------------------
__device__ __forceinline__ float sum16d(float v) {
  v += __int_as_float(__builtin_amdgcn_update_dpp(0, __float_as_int(v), 0xB1, 0xF, 0xF, true));   // xor 1
  v += __int_as_float(__builtin_amdgcn_update_dpp(0, __float_as_int(v), 0x4E, 0xF, 0xF, true));   // xor 2
  v += __int_as_float(__builtin_amdgcn_update_dpp(0, __float_as_int(v), 0x128, 0xF, 0xF, true));  // row_ror:8 == xor 8
  v += __int_as_float(__builtin_amdgcn_ds_swizzle(__float_as_int(v), 0x101F));                    // xor 4
  return v;
}

struct Buf { f32x4 kn[2]; f32x4 q[2]; float v, bx; };

__device__ __forceinline__ void load_buf(const float* __restrict__ p, int cc, int row, Buf& b) {
  const f32x4* p4 = reinterpret_cast<const f32x4*>(p);
  b.kn[0] = p4[cc * 2 + 0];
  b.kn[1] = p4[cc * 2 + 1];
  b.q[0]  = p4[64 + cc * 2 + 0];
  b.q[1]  = p4[64 + cc * 2 + 1];
  b.v  = p[128 + row];
  b.bx = p[384 + row];
}

__device__ __forceinline__ float core(const Buf& b, float db, float bb, f32x2 S2[4]) {
  const f32x2 k0 = {b.kn[0].x, b.kn[0].y}, k1 = {b.kn[0].z, b.kn[0].w};
  const f32x2 k2 = {b.kn[1].x, b.kn[1].y}, k3 = {b.kn[1].z, b.kn[1].w};
  f32x2 a0 = S2[0] * k0;
  f32x2 a1 = S2[1] * k1;
  a0 = __builtin_elementwise_fma(S2[2], k2, a0);
  a1 = __builtin_elementwise_fma(S2[3], k3, a1);
  const f32x2 ac = a0 + a1;
  const float r = sum16d(ac.x + ac.y);
  const float lg = fmaf(db, r, b.bx + bb);
  const float beta = __builtin_amdgcn_rcpf(1.0f + __expf(-lg));
  const float cr = beta * (b.v - r);
  const f32x2 cr2 = {cr, cr};
  S2[0] = __builtin_elementwise_fma(cr2, k0, S2[0]);
  S2[1] = __builtin_elementwise_fma(cr2, k1, S2[1]);
  S2[2] = __builtin_elementwise_fma(cr2, k2, S2[2]);
  S2[3] = __builtin_elementwise_fma(cr2, k3, S2[3]);
  const f32x2 q0 = {b.q[0].x, b.q[0].y}, q1 = {b.q[0].z, b.q[0].w};
  const f32x2 q2 = {b.q[1].x, b.q[1].y}, q3 = {b.q[1].z, b.q[1].w};
  f32x2 o0 = S2[0] * q0;
  f32x2 o1 = S2[1] * q1;
  o0 = __builtin_elementwise_fma(S2[2], q2, o0);
  o1 = __builtin_elementwise_fma(S2[3], q3, o1);
  const f32x2 ao = o0 + o1;
  return sum16d(ao.x + ao.y);                      // raw od; silu deferred
}

__device__ __forceinline__ float fin(float od) {
  return od * od * __builtin_amdgcn_rcpf(1.0f + __expf(-od));
}

__global__ __launch_bounds__(64) void scan_kernel(
    const float* __restrict__ proj, const float* __restrict__ S_in,
    const float* __restrict__ d_beta, const float* __restrict__ b_beta,
    float* __restrict__ out, float* __restrict__ S_out)
{
  const int lane = threadIdx.x & 63;
  const int batch = blockIdx.x & 15;       // batches b, b+8 share XCD b%8
  const int grp = blockIdx.x >> 4;         // 0..31 row-group of 4
  const int cc = lane & 15;                // col chunk: 8 floats
  const int rloc = lane >> 4;              // 0..3
  const int row = grp * 4 + rloc;
  const bool w0 = (cc == 0);               // one lane per row stores

  f32x2 S2[4];
  {
    const f32x4* Sp4 = reinterpret_cast<const f32x4*>(
        S_in + ((size_t)batch * ND + row) * ND + cc * 8);
    const f32x4 s0 = Sp4[0], s1 = Sp4[1];
    S2[0] = (f32x2){s0.x, s0.y}; S2[1] = (f32x2){s0.z, s0.w};
    S2[2] = (f32x2){s1.x, s1.y}; S2[3] = (f32x2){s1.z, s1.w};
  }
  const float db = d_beta[row];
  const float bb = b_beta[row];

  const float* pb = proj + (size_t)batch * PSTRIDE;
  const size_t sstep = (size_t)NB * PSTRIDE;
  float* outp = out + (size_t)batch * ND + row;
  const size_t ostep = (size_t)NB * ND;

  Buf A, B, C, D;
  __builtin_amdgcn_sched_barrier(0);
  load_buf(pb + 0 * sstep, cc, row, A);
  load_buf(pb + 1 * sstep, cc, row, B);
  load_buf(pb + 2 * sstep, cc, row, C);
  load_buf(pb + 3 * sstep, cc, row, D);
  __builtin_amdgcn_sched_barrier(0);

  float od_prev;

#define SLOT(BUF, tnext)                                                  \
  do {                                                                    \
    const float gprev = fin(od_prev);                                     \
    if (w0) *outp = gprev;                                                \
    outp += ostep;                                                        \
    od_prev = core(BUF, db, bb, S2);                                      \
    __builtin_amdgcn_sched_barrier(0);                                    \
    load_buf(pb + (size_t)(tnext) * sstep, cc, row, BUF);                 \
    __builtin_amdgcn_sched_barrier(0);                                    \
  } while (0)

  // peel: step 0 has no pending store
  od_prev = core(A, db, bb, S2);
  __builtin_amdgcn_sched_barrier(0);
  load_buf(pb + 4 * sstep, cc, row, A);
  __builtin_amdgcn_sched_barrier(0);
  SLOT(B, 5);
  SLOT(C, 6);
  SLOT(D, 7);

  for (int t = 4; t < T_STEPS; t += 4) {
    const int t4 = (t + 4 < T_STEPS) ? t + 4 : T_STEPS - 1;
    const int t5 = (t + 5 < T_STEPS) ? t + 5 : T_STEPS - 1;
    const int t6 = (t + 6 < T_STEPS) ? t + 6 : T_STEPS - 1;
    const int t7 = (t + 7 < T_STEPS) ? t + 7 : T_STEPS - 1;
    SLOT(A, t4);
    SLOT(B, t5);
    SLOT(C, t6);
    SLOT(D, t7);
  }
  // final pending store (step 2047)
  {
    const float g = fin(od_prev);
    if (w0) *outp = g;
  }
#undef SLOT

  {
    f32x4* So4 = reinterpret_cast<f32x4*>(
        S_out + ((size_t)batch * ND + row) * ND + cc * 8);
    f32x4 s0, s1;
    s0.x = S2[0].x; s0.y = S2[0].y; s0.z = S2[1].x; s0.w = S2[1].y;
    s1.x = S2[2].x; s1.y = S2[2].y; s1.z = S2[3].x; s1.w = S2[3].y;
    So4[0] = s0; So4[1] = s1;
  }
}

extern "C" void kernel_launch(void* const* d_in, const int* in_sizes, int n_in,
                              void* d_out, int out_size, void* d_ws, size_t ws_size,
                              hipStream_t stream) {
  const float* x  = (const float*)d_in[0];   // [2048][16][1024]
  const float* S0 = (const float*)d_in[1];   // [16][128][128]
  const float* Wk = (const float*)d_in[2];
  const float* Wv = (const float*)d_in[3];
  const float* Wq = (const float*)d_in[4];
  const float* Wb = (const float*)d_in[5];
  const float* db = (const float*)d_in[6];
  const float* bb = (const float*)d_in[7];
  float* out  = (float*)d_out;                           // [2048][16][128]
  float* Sout = out + (size_t)T_STEPS * NB * ND;         // [16][128][128]
  float* proj = (float*)d_ws;                            // [32768][512] = 64 MB

  dim3 ggrid(256, 4);
  proj_gemm<<<ggrid, 256, 0, stream>>>(x, Wk, Wv, Wq, Wb, proj);
  norm_k<<<8192, 256, 0, stream>>>(proj);
  scan_kernel<<<512, 64, 0, stream>>>(proj, S0, db, bb, out, Sout);
}

// Round 7
// 406.887 us; speedup vs baseline: 16.6002x; 1.2580x over previous
//
#include <hip/hip_runtime.h>
#include <hip/hip_bf16.h>

// E71 Delta cell: T=2048, B=16, D=1024, N=128
// proj layout in ws: [t][b][512] f32, cols 0..127=k_hat (after norm pass),
// 128..255=v, 256..383=q, 384..511=bx

#define T_STEPS 2048
#define NB 16
#define ND 128
#define KD 1024
#define PSTRIDE 512

typedef __attribute__((ext_vector_type(4))) float f32x4;
typedef __attribute__((ext_vector_type(2))) float f32x2;
typedef __attribute__((ext_vector_type(8))) short short8v;

__device__ __forceinline__ unsigned short f2bf(float f) {
  union { float f; unsigned int u; } c; c.f = f;
  unsigned int u = c.u;
  unsigned int r = u + 0x7fffu + ((u >> 16) & 1u);   // round-to-nearest-even
  return (unsigned short)(r >> 16);
}

// ---------------------------------------------------------------------------
// Projection GEMM (unchanged, ~56us): bf16 MFMA, 128x128 tile, BK=64,
// XOR-swizzled LDS.
// ---------------------------------------------------------------------------
__global__ __launch_bounds__(256) void proj_gemm(
    const float* __restrict__ X,
    const float* __restrict__ Wk, const float* __restrict__ Wv,
    const float* __restrict__ Wq, const float* __restrict__ Wb,
    float* __restrict__ C)
{
  __shared__ unsigned short As[128 * 64];
  __shared__ unsigned short Bs[128 * 64];
  const int tid = threadIdx.x;
  const int bm = blockIdx.x;
  const int bn = blockIdx.y;
  const float* W = (bn == 0) ? Wk : ((bn == 1) ? Wv : ((bn == 2) ? Wq : Wb));
  const int lane = tid & 63;
  const int wave = tid >> 6;
  const int wr = wave >> 1, wc = wave & 1;

  f32x4 acc[4][4];
#pragma unroll
  for (int i = 0; i < 4; i++)
#pragma unroll
    for (int j = 0; j < 4; j++) acc[i][j] = (f32x4){0.f, 0.f, 0.f, 0.f};

  for (int k0 = 0; k0 < KD; k0 += 64) {
    __syncthreads();
#pragma unroll
    for (int c = 0; c < 4; c++) {
      const int g = tid + c * 256;
      const int row = g >> 3;
      const int ch = g & 7;
      const int pos = ((ch ^ (row & 7)) * 8);
      {
        const float* ga = X + (size_t)(bm * 128 + row) * KD + k0 + ch * 8;
        float4 f0 = *(const float4*)(ga);
        float4 f1 = *(const float4*)(ga + 4);
        union { unsigned short u[8]; short8v v; } pk2;
        pk2.u[0] = f2bf(f0.x); pk2.u[1] = f2bf(f0.y);
        pk2.u[2] = f2bf(f0.z); pk2.u[3] = f2bf(f0.w);
        pk2.u[4] = f2bf(f1.x); pk2.u[5] = f2bf(f1.y);
        pk2.u[6] = f2bf(f1.z); pk2.u[7] = f2bf(f1.w);
        *reinterpret_cast<short8v*>(&As[row * 64 + pos]) = pk2.v;
      }
      {
        const float* gb = W + (size_t)row * KD + k0 + ch * 8;
        float4 f0 = *(const float4*)(gb);
        float4 f1 = *(const float4*)(gb + 4);
        union { unsigned short u[8]; short8v v; } pk2;
        pk2.u[0] = f2bf(f0.x); pk2.u[1] = f2bf(f0.y);
        pk2.u[2] = f2bf(f0.z); pk2.u[3] = f2bf(f0.w);
        pk2.u[4] = f2bf(f1.x); pk2.u[5] = f2bf(f1.y);
        pk2.u[6] = f2bf(f1.z); pk2.u[7] = f2bf(f1.w);
        *reinterpret_cast<short8v*>(&Bs[row * 64 + pos]) = pk2.v;
      }
    }
    __syncthreads();
#pragma unroll
    for (int kk = 0; kk < 2; kk++) {
      const int ch = kk * 4 + (lane >> 4);
      short8v a[4], b[4];
#pragma unroll
      for (int i = 0; i < 4; i++) {
        const int ar = wr * 64 + i * 16 + (lane & 15);
        a[i] = *reinterpret_cast<const short8v*>(&As[ar * 64 + ((ch ^ (ar & 7)) * 8)]);
        const int br = wc * 64 + i * 16 + (lane & 15);
        b[i] = *reinterpret_cast<const short8v*>(&Bs[br * 64 + ((ch ^ (br & 7)) * 8)]);
      }
#pragma unroll
      for (int i = 0; i < 4; i++)
#pragma unroll
        for (int j = 0; j < 4; j++)
          acc[i][j] = __builtin_amdgcn_mfma_f32_16x16x32_bf16(a[i], b[j], acc[i][j], 0, 0, 0);
    }
  }
#pragma unroll
  for (int i = 0; i < 4; i++)
#pragma unroll
    for (int j = 0; j < 4; j++)
#pragma unroll
      for (int r = 0; r < 4; r++) {
        const int row = bm * 128 + wr * 64 + i * 16 + (lane >> 4) * 4 + r;
        const int col = bn * 128 + wc * 64 + j * 16 + (lane & 15);
        C[(size_t)row * PSTRIDE + col] = acc[i][j][r];
      }
}

// ---------------------------------------------------------------------------
// k-normalization pre-pass: proj[row][0:128] <- k / (||k|| + eps).
// ---------------------------------------------------------------------------
__global__ __launch_bounds__(256) void norm_k(float* __restrict__ proj) {
  const int lane = threadIdx.x & 63;
  const int wid = (blockIdx.x * 256 + threadIdx.x) >> 6;
  float* rowp = proj + (size_t)wid * PSTRIDE;
  float2 kv = *reinterpret_cast<float2*>(rowp + lane * 2);
  float ss = kv.x * kv.x + kv.y * kv.y;
  ss += __shfl_xor(ss, 1);
  ss += __shfl_xor(ss, 2);
  ss += __shfl_xor(ss, 4);
  ss += __shfl_xor(ss, 8);
  ss += __shfl_xor(ss, 16);
  ss += __shfl_xor(ss, 32);
  const float rn = 1.0f / (sqrtf(ss) + 1e-6f);
  kv.x *= rn; kv.y *= rn;
  *reinterpret_cast<float2*>(rowp + lane * 2) = kv;
}

// ---------------------------------------------------------------------------
// Sequential scan, pure-register, zero LDS/DS ops, zero barriers.
// Geometry (R6): 512 blocks x 64 thr; block = (batch, 4-row group);
//   16 lanes/row (cc = lane&15 -> 8 cols), rloc = lane>>4.
// R7 fixes:
//  - asm volatile global_load prefetch (IR passes CANNOT sink inline asm;
//    R4/R6's plain loads were sunk despite sched_barrier -> VGPR 52).
//    Manual counted s_waitcnt vmcnt(18) + sched_barrier(0) after (rule #18).
//  - sum16: rotation reduce row_ror:8/4/2/1 - all DPP/VALU, no ds_swizzle
//    (DS-pipe ~100cy latency was on the recurrence chain twice).
//  - od reduce + silu + store stay off the recurrence chain (deferred).
// ---------------------------------------------------------------------------
__device__ __forceinline__ float sum16r(float v) {
  v += __int_as_float(__builtin_amdgcn_update_dpp(0, __float_as_int(v), 0x128, 0xF, 0xF, true)); // row_ror:8
  v += __int_as_float(__builtin_amdgcn_update_dpp(0, __float_as_int(v), 0x124, 0xF, 0xF, true)); // row_ror:4
  v += __int_as_float(__builtin_amdgcn_update_dpp(0, __float_as_int(v), 0x122, 0xF, 0xF, true)); // row_ror:2
  v += __int_as_float(__builtin_amdgcn_update_dpp(0, __float_as_int(v), 0x121, 0xF, 0xF, true)); // row_ror:1
  return v;
}

struct Buf { f32x4 kn0, kn1, q0, q1; float v, bx; };

// pk = row base + cc*8 floats; pv = row base + row (scalar lane base).
// k at +0,+16B; q at +1024,+1040B; v at +512B; bx at +1536B (13-bit imm ok).
__device__ __forceinline__ void load_buf_asm(const float* pk, const float* pv, Buf& b) {
  asm volatile("global_load_dwordx4 %0, %1, off"             : "=v"(b.kn0) : "v"(pk));
  asm volatile("global_load_dwordx4 %0, %1, off offset:16"   : "=v"(b.kn1) : "v"(pk));
  asm volatile("global_load_dwordx4 %0, %1, off offset:1024" : "=v"(b.q0)  : "v"(pk));
  asm volatile("global_load_dwordx4 %0, %1, off offset:1040" : "=v"(b.q1)  : "v"(pk));
  asm volatile("global_load_dword %0, %1, off offset:512"    : "=v"(b.v)   : "v"(pv));
  asm volatile("global_load_dword %0, %1, off offset:1536"   : "=v"(b.bx)  : "v"(pv));
}

__device__ __forceinline__ float core(const Buf& b, float db, float bb, f32x2 S2[4]) {
  const f32x2 k0 = {b.kn0.x, b.kn0.y}, k1 = {b.kn0.z, b.kn0.w};
  const f32x2 k2 = {b.kn1.x, b.kn1.y}, k3 = {b.kn1.z, b.kn1.w};
  f32x2 a0 = S2[0] * k0;
  f32x2 a1 = S2[1] * k1;
  a0 = __builtin_elementwise_fma(S2[2], k2, a0);
  a1 = __builtin_elementwise_fma(S2[3], k3, a1);
  const f32x2 ac = a0 + a1;
  const float r = sum16r(ac.x + ac.y);
  const float lg = fmaf(db, r, b.bx + bb);
  const float beta = __builtin_amdgcn_rcpf(1.0f + __expf(-lg));
  const float cr = beta * (b.v - r);
  const f32x2 cr2 = {cr, cr};
  S2[0] = __builtin_elementwise_fma(cr2, k0, S2[0]);
  S2[1] = __builtin_elementwise_fma(cr2, k1, S2[1]);
  S2[2] = __builtin_elementwise_fma(cr2, k2, S2[2]);
  S2[3] = __builtin_elementwise_fma(cr2, k3, S2[3]);
  const f32x2 q0 = {b.q0.x, b.q0.y}, q1 = {b.q0.z, b.q0.w};
  const f32x2 q2 = {b.q1.x, b.q1.y}, q3 = {b.q1.z, b.q1.w};
  f32x2 o0 = S2[0] * q0;
  f32x2 o1 = S2[1] * q1;
  o0 = __builtin_elementwise_fma(S2[2], q2, o0);
  o1 = __builtin_elementwise_fma(S2[3], q3, o1);
  const f32x2 ao = o0 + o1;
  return sum16r(ao.x + ao.y);                      // raw od; silu deferred
}

__device__ __forceinline__ float fin(float od) {
  return od * od * __builtin_amdgcn_rcpf(1.0f + __expf(-od));
}

__global__ __launch_bounds__(64) void scan_kernel(
    const float* __restrict__ proj, const float* __restrict__ S_in,
    const float* __restrict__ d_beta, const float* __restrict__ b_beta,
    float* __restrict__ out, float* __restrict__ S_out)
{
  const int lane = threadIdx.x & 63;
  const int batch = blockIdx.x & 15;       // batches b, b+8 share XCD b%8
  const int grp = blockIdx.x >> 4;         // 0..31 row-group of 4
  const int cc = lane & 15;                // col chunk: 8 floats
  const int rloc = lane >> 4;              // 0..3
  const int row = grp * 4 + rloc;
  const bool w0 = (cc == 0);               // one lane per row stores

  f32x2 S2[4];
  {
    const f32x4* Sp4 = reinterpret_cast<const f32x4*>(
        S_in + ((size_t)batch * ND + row) * ND + cc * 8);
    const f32x4 s0 = Sp4[0], s1 = Sp4[1];
    S2[0] = (f32x2){s0.x, s0.y}; S2[1] = (f32x2){s0.z, s0.w};
    S2[2] = (f32x2){s1.x, s1.y}; S2[3] = (f32x2){s1.z, s1.w};
  }
  const float db = d_beta[row];
  const float bb = b_beta[row];

  const float* pb = proj + (size_t)batch * PSTRIDE;
  const float* pkb = pb + cc * 8;          // vector lane base
  const float* pvb = pb + row;             // scalar lane base
  const size_t sstep = (size_t)NB * PSTRIDE;
  float* outp = out + (size_t)batch * ND + row;
  const size_t ostep = (size_t)NB * ND;

  Buf A, B, C, D;
  load_buf_asm(pkb + 0 * sstep, pvb + 0 * sstep, A);
  load_buf_asm(pkb + 1 * sstep, pvb + 1 * sstep, B);
  load_buf_asm(pkb + 2 * sstep, pvb + 2 * sstep, C);
  load_buf_asm(pkb + 3 * sstep, pvb + 3 * sstep, D);

  float od_prev;

#define WAIT18 do { asm volatile("s_waitcnt vmcnt(18)" ::: "memory"); \
                    __builtin_amdgcn_sched_barrier(0); } while (0)

#define SLOT(BUF, tnext)                                                  \
  do {                                                                    \
    const float gprev = fin(od_prev);                                     \
    if (w0) *outp = gprev;                                                \
    outp += ostep;                                                        \
    WAIT18;                                                               \
    od_prev = core(BUF, db, bb, S2);                                      \
    __builtin_amdgcn_sched_barrier(0);                                    \
    load_buf_asm(pkb + (size_t)(tnext) * sstep,                           \
                 pvb + (size_t)(tnext) * sstep, BUF);                     \
    __builtin_amdgcn_sched_barrier(0);                                    \
  } while (0)

  // peel: step 0 (no pending store)
  WAIT18;
  od_prev = core(A, db, bb, S2);
  __builtin_amdgcn_sched_barrier(0);
  load_buf_asm(pkb + 4 * sstep, pvb + 4 * sstep, A);
  __builtin_amdgcn_sched_barrier(0);
  SLOT(B, 5);
  SLOT(C, 6);
  SLOT(D, 7);

  // steady state: steps 4..2043, loads up to 2047
  for (int t = 4; t + 8 <= T_STEPS; t += 4) {
    SLOT(A, t + 4);
    SLOT(B, t + 5);
    SLOT(C, t + 6);
    SLOT(D, t + 7);
  }

  // tail: steps 2044..2047, no further loads; drain once
  {
    const float g = fin(od_prev);
    if (w0) *outp = g;
    outp += ostep;
  }
  asm volatile("s_waitcnt vmcnt(0)" ::: "memory");
  __builtin_amdgcn_sched_barrier(0);
  od_prev = core(A, db, bb, S2);
  { const float g = fin(od_prev); if (w0) *outp = g; outp += ostep; }
  od_prev = core(B, db, bb, S2);
  { const float g = fin(od_prev); if (w0) *outp = g; outp += ostep; }
  od_prev = core(C, db, bb, S2);
  { const float g = fin(od_prev); if (w0) *outp = g; outp += ostep; }
  od_prev = core(D, db, bb, S2);
  { const float g = fin(od_prev); if (w0) *outp = g; }
#undef SLOT
#undef WAIT18

  {
    f32x4* So4 = reinterpret_cast<f32x4*>(
        S_out + ((size_t)batch * ND + row) * ND + cc * 8);
    f32x4 s0, s1;
    s0.x = S2[0].x; s0.y = S2[0].y; s0.z = S2[1].x; s0.w = S2[1].y;
    s1.x = S2[2].x; s1.y = S2[2].y; s1.z = S2[3].x; s1.w = S2[3].y;
    So4[0] = s0; So4[1] = s1;
  }
}

extern "C" void kernel_launch(void* const* d_in, const int* in_sizes, int n_in,
                              void* d_out, int out_size, void* d_ws, size_t ws_size,
                              hipStream_t stream) {
  const float* x  = (const float*)d_in[0];   // [2048][16][1024]
  const float* S0 = (const float*)d_in[1];   // [16][128][128]
  const float* Wk = (const float*)d_in[2];
  const float* Wv = (const float*)d_in[3];
  const float* Wq = (const float*)d_in[4];
  const float* Wb = (const float*)d_in[5];
  const float* db = (const float*)d_in[6];
  const float* bb = (const float*)d_in[7];
  float* out  = (float*)d_out;                           // [2048][16][128]
  float* Sout = out + (size_t)T_STEPS * NB * ND;         // [16][128][128]
  float* proj = (float*)d_ws;                            // [32768][512] = 64 MB

  dim3 ggrid(256, 4);
  proj_gemm<<<ggrid, 256, 0, stream>>>(x, Wk, Wv, Wq, Wb, proj);
  norm_k<<<8192, 256, 0, stream>>>(proj);
  scan_kernel<<<512, 64, 0, stream>>>(proj, S0, db, bb, out, Sout);
}